// Round 1
// baseline (399.800 us; speedup 1.0000x reference)
//
#include <hip/hip_runtime.h>
#include <math.h>

// Problem constants (from reference setup_inputs):
//   feat:      [N=256, C=2048, H=16, W=8]  fp32
//   scoremap:  [N=256, K=13, H=16, W=8]    fp32
//   conf:      [N=256, K=13]               fp32
// Outputs (concat flat): feat_vecs [N,14,C] fp32, conf_out [N,14] fp32.

#define N_   256
#define C_   2048
#define K_   13
#define HW_  128
#define CTILE 256      // channels per block
#define CHUNK 32       // hw per staged chunk
#define NCHUNK (HW_ / CHUNK)
#define PAD  (CHUNK + 1)   // LDS row stride: (33c+hw)%32 = (c+hw)%32 -> <=2-way, free
#define TILES_PER_N (C_ / CTILE)   // 8

__global__ __launch_bounds__(CTILE) void horeid_main(
    const float* __restrict__ feat,
    const float* __restrict__ scoremap,
    const float* __restrict__ kconf,
    float* __restrict__ out)
{
    __shared__ float lds[CTILE * PAD];   // 33,792 B -> 4 blocks/CU by LDS

    const int tid  = threadIdx.x;
    const int n    = blockIdx.x >> 3;          // TILES_PER_N == 8
    const int tile = blockIdx.x & (TILES_PER_N - 1);
    const int c0   = tile * CTILE;

    const float* featn = feat + (size_t)n * C_ * HW_ + (size_t)c0 * HW_;
    const float* scn   = scoremap + (size_t)n * K_ * HW_;   // wave-uniform base

    float acc[K_];
    #pragma unroll
    for (int k = 0; k < K_; ++k) acc[k] = 0.0f;
    float fsum = 0.0f;
    float fmx  = -INFINITY;

    // Staging map: 2048 float4 per chunk; thread t handles float4 idx t+256*i.
    // row = idx>>3 (8 float4 per 32-float row), col = idx&7 (constant per thread).
    const int srow = tid >> 3;
    const int scol = tid & 7;

    for (int ch = 0; ch < NCHUNK; ++ch) {
        __syncthreads();   // LDS reuse guard (no-op cost on ch==0)
        #pragma unroll
        for (int i = 0; i < 8; ++i) {
            const int r = srow + (i << 5);
            // 8 lanes x float4 = one aligned 128 B line per channel-row slice
            const float4 v = *(const float4*)(featn + (size_t)r * HW_ + ch * CHUNK + (scol << 2));
            float* dst = &lds[r * PAD + (scol << 2)];
            dst[0] = v.x; dst[1] = v.y; dst[2] = v.z; dst[3] = v.w;
        }
        __syncthreads();

        const float* myrow = &lds[tid * PAD];
        #pragma unroll
        for (int i = 0; i < CHUNK; ++i) {
            const int hw = ch * CHUNK + i;     // wave-uniform
            const float f = myrow[i];
            fsum += f;
            fmx = fmaxf(fmx, f);
            #pragma unroll
            for (int k = 0; k < K_; ++k)       // scn[..] wave-uniform -> s_load
                acc[k] = fmaf(scn[k * HW_ + hw], f, acc[k]);
        }
    }

    // feat_vecs [N,14,C]: coalesced along c
    float* outn = out + (size_t)n * 14 * C_ + c0 + tid;
    #pragma unroll
    for (int k = 0; k < K_; ++k) outn[(size_t)k * C_] = acc[k];
    outn[(size_t)13 * C_] = fsum * (1.0f / HW_) + fmx;   // GAP + GMP

    // conf_out [N,14], appended after feat_vecs; one tile per n does it
    if (tile == 0 && tid < 14) {
        float s = 0.0f;
        #pragma unroll
        for (int j = 0; j < K_; ++j) s += fabsf(kconf[n * K_ + j]);
        s = fmaxf(s, 1e-12f);
        const float v = (tid < K_) ? kconf[n * K_ + tid] / s : 1.0f;
        out[(size_t)N_ * 14 * C_ + n * 14 + tid] = v;
    }
}

extern "C" void kernel_launch(void* const* d_in, const int* in_sizes, int n_in,
                              void* d_out, int out_size, void* d_ws, size_t ws_size,
                              hipStream_t stream) {
    const float* feat  = (const float*)d_in[0];
    const float* sc    = (const float*)d_in[1];
    const float* kconf = (const float*)d_in[2];
    float* out = (float*)d_out;
    horeid_main<<<dim3(N_ * TILES_PER_N), dim3(CTILE), 0, stream>>>(feat, sc, kconf, out);
}

// Round 2
// 381.125 us; speedup vs baseline: 1.0490x; 1.0490x over previous
//
#include <hip/hip_runtime.h>
#include <math.h>

// feat: [N=256, C=2048, H*W=128] fp32; scoremap: [N,13,128]; conf: [N,13]
// out: feat_vecs [N,14,C] fp32 ++ conf_out [N,14] fp32 (flat concat)

#define N_    256
#define C_    2048
#define K_    13
#define HW_   128
#define CTILE 1024          // channels per block
#define RPT   4             // channels per thread (256 threads)
#define CHUNK 16            // hw per staged chunk
#define NCHUNK (HW_ / CHUNK)      // 8
#define PAD   (CHUNK + 1)         // 17-float row stride (odd -> conflict-free-ish)
#define TILES_PER_N (C_ / CTILE)  // 2

__global__ __launch_bounds__(256) void horeid_main(
    const float* __restrict__ feat,
    const float* __restrict__ scoremap,
    const float* __restrict__ kconf,
    float* __restrict__ out)
{
    __shared__ float sfeat[CTILE * PAD];   // 69,632 B
    __shared__ float ssc[K_ * HW_];        // 6,656 B  (total 76.3 KB -> 2 blocks/CU)

    const int tid  = threadIdx.x;
    const int n    = blockIdx.x >> 1;            // TILES_PER_N == 2
    const int tile = blockIdx.x & 1;
    const int c0   = tile * CTILE;

    const float* featn = feat + (size_t)n * C_ * HW_ + (size_t)c0 * HW_;
    const float* scn   = scoremap + (size_t)n * K_ * HW_;

    // Stage all of scoremap[n] into LDS once (416 float4, coalesced).
    for (int idx = tid; idx < (K_ * HW_) / 4; idx += 256)
        ((float4*)ssc)[idx] = ((const float4*)scn)[idx];
    // (covered by the ch==0 barrier below)

    float acc[K_][RPT];
    #pragma unroll
    for (int k = 0; k < K_; ++k)
        #pragma unroll
        for (int r = 0; r < RPT; ++r) acc[k][r] = 0.0f;
    float fsum[RPT], fmx[RPT];
    #pragma unroll
    for (int r = 0; r < RPT; ++r) { fsum[r] = 0.0f; fmx[r] = -INFINITY; }

    // Staging map: 4096 float4/chunk; thread t does idx = t + 256*i:
    // row = idx>>2 (4 float4 per 16-float row), col = (t&3)*4 (constant).
    const int srow0 = tid >> 2;
    const int scol  = (tid & 3) << 2;

    for (int ch = 0; ch < NCHUNK; ++ch) {
        __syncthreads();                        // reuse guard (+ covers ssc staging at ch==0)
        #pragma unroll
        for (int i = 0; i < 16; ++i) {
            const int r = srow0 + (i << 6);
            const float4 v = *(const float4*)(featn + (size_t)r * HW_ + ch * CHUNK + scol);
            *(float4*)(&sfeat[r * PAD + scol]) = v;
        }
        __syncthreads();

        #pragma unroll
        for (int g = 0; g < 4; ++g) {           // 4 hw per group
            const int hw0 = ch * CHUNK + (g << 2);
            float4 s4[K_];
            #pragma unroll
            for (int k = 0; k < K_; ++k)        // uniform addr -> LDS broadcast
                s4[k] = *(const float4*)(&ssc[k * HW_ + hw0]);
            #pragma unroll
            for (int r = 0; r < RPT; ++r) {
                const float4 f = *(const float4*)(&sfeat[(tid + (r << 8)) * PAD + (g << 2)]);
                fsum[r] += (f.x + f.y) + (f.z + f.w);
                fmx[r] = fmaxf(fmx[r], fmaxf(fmaxf(f.x, f.y), fmaxf(f.z, f.w)));
                #pragma unroll
                for (int k = 0; k < K_; ++k)
                    acc[k][r] = fmaf(s4[k].x, f.x,
                                fmaf(s4[k].y, f.y,
                                fmaf(s4[k].z, f.z,
                                fmaf(s4[k].w, f.w, acc[k][r]))));
            }
        }
    }

    // feat_vecs [N,14,C]: coalesced along c
    float* outn = out + (size_t)n * 14 * C_ + c0 + tid;
    #pragma unroll
    for (int r = 0; r < RPT; ++r) {
        #pragma unroll
        for (int k = 0; k < K_; ++k) outn[(size_t)k * C_ + (r << 8)] = acc[k][r];
        outn[(size_t)13 * C_ + (r << 8)] = fsum[r] * (1.0f / HW_) + fmx[r];  // GAP + GMP
    }

    // conf_out [N,14] appended after feat_vecs; one tile per n writes it
    if (tile == 0 && tid < 14) {
        float s = 0.0f;
        #pragma unroll
        for (int j = 0; j < K_; ++j) s += fabsf(kconf[n * K_ + j]);
        s = fmaxf(s, 1e-12f);
        const float v = (tid < K_) ? kconf[n * K_ + tid] / s : 1.0f;
        out[(size_t)N_ * 14 * C_ + n * 14 + tid] = v;
    }
}

extern "C" void kernel_launch(void* const* d_in, const int* in_sizes, int n_in,
                              void* d_out, int out_size, void* d_ws, size_t ws_size,
                              hipStream_t stream) {
    const float* feat  = (const float*)d_in[0];
    const float* sc    = (const float*)d_in[1];
    const float* kconf = (const float*)d_in[2];
    float* out = (float*)d_out;
    horeid_main<<<dim3(N_ * TILES_PER_N), dim3(256), 0, stream>>>(feat, sc, kconf, out);
}

// Round 3
// 370.862 us; speedup vs baseline: 1.0780x; 1.0277x over previous
//
#include <hip/hip_runtime.h>
#include <math.h>

// feat: [N=256, C=2048, HW=128] fp32; scoremap: [N,13,128]; conf: [N,13]
// out (flat): feat_vecs [N,14,C] fp32 ++ conf_out [N,14] fp32
//
// Scheme B: barrier-free feat streaming.
//  - 8 lanes per channel: lane j covers hw = p*32 + j*4 .. +3 (p=0..3).
//  - feat read directly from global, coalesced (8 channels x 128B lines/instr).
//  - scoremap[n] (6.6 KB) staged to LDS once; ds_read_b128 with 8 distinct
//    addrs spanning all 32 banks, 8-way broadcast -> conflict-free.
//  - 15-value per-channel reduce across the 8 lanes via DPP (VALU pipe):
//    quad_perm xor1, xor2, row_half_mirror.

#define N_     256
#define C_     2048
#define K_     13
#define HW_    128
#define TILES  4        // channel tiles per n (512 ch each); grid = N_*TILES
#define PASSES 4        // per wave: 128 ch = 4 passes x 32 ch (8 groups x R=4)
#define RPT    4

template<int CTRL>
__device__ __forceinline__ float dppf(float x) {
    return __int_as_float(__builtin_amdgcn_update_dpp(
        0, __float_as_int(x), CTRL, 0xF, 0xF, true));
}
__device__ __forceinline__ float sum8(float x) {   // butterfly over 8-lane group
    x += dppf<0xB1>(x);    // quad_perm(1,0,3,2) : xor 1
    x += dppf<0x4E>(x);    // quad_perm(2,3,0,1) : xor 2
    x += dppf<0x141>(x);   // row_half_mirror    : cross-quad within 8
    return x;
}
__device__ __forceinline__ float max8(float x) {
    x = fmaxf(x, dppf<0xB1>(x));
    x = fmaxf(x, dppf<0x4E>(x));
    x = fmaxf(x, dppf<0x141>(x));
    return x;
}

__global__ __launch_bounds__(256) void horeid_main(
    const float* __restrict__ feat,
    const float* __restrict__ scoremap,
    const float* __restrict__ kconf,
    float* __restrict__ out)
{
    __shared__ float ssc[K_ * HW_];   // 6,656 B

    const int tid  = threadIdx.x;
    const int n    = blockIdx.x >> 2;        // TILES == 4
    const int tile = blockIdx.x & 3;

    // Stage scoremap[n] once (416 float4, coalesced).
    {
        const float4* src = (const float4*)(scoremap + (size_t)n * K_ * HW_);
        for (int i = tid; i < (K_ * HW_) / 4; i += 256)
            ((float4*)ssc)[i] = src[i];
    }
    __syncthreads();   // the only barrier

    const int wave = tid >> 6;
    const int lane = tid & 63;
    const int g    = lane >> 3;   // channel group within wave (0..7)
    const int j    = lane & 7;    // hw sub-lane within channel (0..7)

    const float* fbase = feat + (size_t)n * C_ * HW_;

    for (int t = 0; t < PASSES; ++t) {
        const int cbase = tile * 512 + wave * 128 + t * 32;

        float acc[RPT][K_];
        float fs[RPT], fm[RPT];
        #pragma unroll
        for (int r = 0; r < RPT; ++r) {
            fs[r] = 0.0f; fm[r] = -INFINITY;
            #pragma unroll
            for (int k = 0; k < K_; ++k) acc[r][k] = 0.0f;
        }

        #pragma unroll
        for (int p = 0; p < 4; ++p) {
            const int hw0 = p * 32 + j * 4;
            float4 s4[K_];
            #pragma unroll
            for (int k = 0; k < K_; ++k)          // all-32-bank broadcast read
                s4[k] = *(const float4*)(&ssc[k * HW_ + hw0]);
            #pragma unroll
            for (int r = 0; r < RPT; ++r) {
                const int c = cbase + g + r * 8;
                const float4 f = *(const float4*)(fbase + (size_t)c * HW_ + hw0);
                fs[r] += (f.x + f.y) + (f.z + f.w);
                fm[r]  = fmaxf(fm[r], fmaxf(fmaxf(f.x, f.y), fmaxf(f.z, f.w)));
                #pragma unroll
                for (int k = 0; k < K_; ++k)
                    acc[r][k] = fmaf(s4[k].x, f.x,
                                fmaf(s4[k].y, f.y,
                                fmaf(s4[k].z, f.z,
                                fmaf(s4[k].w, f.w, acc[r][k]))));
            }
        }

        // Reduce across the 8 lanes of each group; every lane ends with all
        // totals, then lane j writes k=j and k=8+j (j<6; j==5 -> k=13 global).
        #pragma unroll
        for (int r = 0; r < RPT; ++r) {
            const int c = cbase + g + r * 8;
            float vals[K_];
            #pragma unroll
            for (int k = 0; k < K_; ++k) vals[k] = sum8(acc[r][k]);
            const float glob = sum8(fs[r]) * (1.0f / HW_) + max8(fm[r]);

            float v0 = vals[0];
            #pragma unroll
            for (int k = 1; k < 8; ++k) v0 = (j == k) ? vals[k] : v0;
            float v1 = vals[8];
            v1 = (j == 1) ? vals[9]  : v1;
            v1 = (j == 2) ? vals[10] : v1;
            v1 = (j == 3) ? vals[11] : v1;
            v1 = (j == 4) ? vals[12] : v1;
            v1 = (j == 5) ? glob     : v1;

            float* outn = out + (size_t)n * 14 * C_ + c;
            outn[(size_t)j * C_] = v0;
            if (j < 6) outn[(size_t)(8 + j) * C_] = v1;
        }
    }

    // conf_out [N,14] appended after feat_vecs; one tile per n writes it
    if (tile == 0 && tid < 14) {
        float s = 0.0f;
        #pragma unroll
        for (int q = 0; q < K_; ++q) s += fabsf(kconf[n * K_ + q]);
        s = fmaxf(s, 1e-12f);
        const float v = (tid < K_) ? kconf[n * K_ + tid] / s : 1.0f;
        out[(size_t)N_ * 14 * C_ + n * 14 + tid] = v;
    }
}

extern "C" void kernel_launch(void* const* d_in, const int* in_sizes, int n_in,
                              void* d_out, int out_size, void* d_ws, size_t ws_size,
                              hipStream_t stream) {
    const float* feat  = (const float*)d_in[0];
    const float* sc    = (const float*)d_in[1];
    const float* kconf = (const float*)d_in[2];
    float* out = (float*)d_out;
    horeid_main<<<dim3(N_ * TILES), dim3(256), 0, stream>>>(feat, sc, kconf, out);
}